// Round 1
// baseline (431.398 us; speedup 1.0000x reference)
//
#include <hip/hip_runtime.h>

#define NB 64
#define NT 4096
#define ND 256
#define NM 5461
#define LEAF0 1365

// De-interleave: keep even bits of v, pack them down. c = cbits(m), r = cbits(m>>1).
__device__ __forceinline__ int cbits(unsigned v) {
  v &= 0x55555555u;
  v = (v | (v >> 1)) & 0x33333333u;
  v = (v | (v >> 2)) & 0x0F0F0F0Fu;
  v = (v | (v >> 4)) & 0x00FF00FFu;
  v = (v | (v >> 8)) & 0x0000FFFFu;
  return (int)v;
}

// Pass 1: one wave per token row. Read x[b,n,:] (1 KB coalesced), dot with q[b,:],
// store f64 token score; simultaneously zero-fill the corresponding output row
// (fuses the mandatory 4.29 GB zero write into the same memory pass).
__global__ __launch_bounds__(256) void k_score_zero(
    const float4* __restrict__ x, const float4* __restrict__ q,
    double* __restrict__ tok, float4* __restrict__ outf)
{
  const int lane = threadIdx.x & 63;
  const int w    = threadIdx.x >> 6;
  const int row  = blockIdx.x * 4 + w;        // 0 .. NB*NT-1
  const int b    = row >> 12;                 // NT = 4096
  const long long base = (long long)row * 64; // float4 units per row = 256/4
  float4 xv = x[base + lane];
  float4 qv = q[(b << 6) + lane];
  double d = (double)xv.x * (double)qv.x + (double)xv.y * (double)qv.y
           + (double)xv.z * (double)qv.z + (double)xv.w * (double)qv.w;
  #pragma unroll
  for (int off = 32; off >= 1; off >>= 1) d += __shfl_xor(d, off, 64);
  if (lane == 0) tok[row] = d;
  outf[base + lane] = make_float4(0.f, 0.f, 0.f, 0.f);
}

// Pass 2: one block per batch. Full tree in LDS (f64 scores), visited/selected/
// covered, stable compaction of selected tokens in token order, mask output.
__global__ __launch_bounds__(1024) void k_tree(
    const double* __restrict__ tok, int* __restrict__ sel_list,
    int* __restrict__ Karr, float* __restrict__ out_mask)
{
  __shared__ double s[NM];
  __shared__ unsigned char vis[NM];
  __shared__ unsigned char cov[NM];
  __shared__ unsigned char tmask[NT];
  __shared__ int wbase[17];
  const int b = blockIdx.x;
  const int tid = threadIdx.x;
  const double* tb = tok + b * NT;

  // Leaves: BFS level-6 node i (Morton order) <-> token r*64+c.
  for (int m = tid; m < NT; m += 1024) {
    int c = cbits((unsigned)m);
    int r = cbits((unsigned)m >> 1);
    s[LEAF0 + m] = tb[(r << 6) + c];
  }
  __syncthreads();

  const int loff[8] = {0, 1, 5, 21, 85, 341, 1365, 5461};

  // Bottom-up: equal-area children => parent score = mean of children.
  #pragma unroll
  for (int l = 5; l >= 0; --l) {
    const int off = loff[l], cnt = 1 << (2 * l), ch = loff[l + 1];
    for (int i = tid; i < cnt; i += 1024) {
      const int c4 = ch + (i << 2);
      s[off + i] = 0.25 * (s[c4] + s[c4 + 1] + s[c4 + 2] + s[c4 + 3]);
    }
    __syncthreads();
  }

  // visited: root true; node iff parent visited && s[node] > s[parent].
  if (tid == 0) vis[0] = 1;
  __syncthreads();
  #pragma unroll
  for (int l = 1; l <= 6; ++l) {
    const int off = loff[l], cnt = 1 << (2 * l), po = loff[l - 1];
    for (int i = tid; i < cnt; i += 1024) {
      const int p = po + (i >> 2);
      vis[off + i] = (vis[p] && (s[off + i] > s[p])) ? 1 : 0;
    }
    __syncthreads();
  }

  // covered top-down; selected computed on the fly:
  // selected = visited && !(any child score > own score); leaves: selected = visited.
  if (tid == 0) {
    const bool ab = (s[1] > s[0]) || (s[2] > s[0]) || (s[3] > s[0]) || (s[4] > s[0]);
    cov[0] = (vis[0] && !ab) ? 1 : 0;
  }
  __syncthreads();
  #pragma unroll
  for (int l = 1; l <= 6; ++l) {
    const int off = loff[l], cnt = 1 << (2 * l), po = loff[l - 1];
    for (int i = tid; i < cnt; i += 1024) {
      const int m = off + i;
      const int p = po + (i >> 2);
      bool selm;
      if (l == 6) {
        selm = vis[m] != 0;
      } else {
        const int c4 = loff[l + 1] + (i << 2);
        const bool ab = (s[c4] > s[m]) || (s[c4 + 1] > s[m]) ||
                        (s[c4 + 2] > s[m]) || (s[c4 + 3] > s[m]);
        selm = vis[m] && !ab;
      }
      const unsigned char cv = (selm || cov[p]) ? 1 : 0;
      cov[m] = cv;
      if (l == 6) {
        const int c = cbits((unsigned)i);
        const int r = cbits((unsigned)i >> 1);
        tmask[(r << 6) + c] = cv;
      }
    }
    __syncthreads();
  }

  // Stable compaction in ascending token order: thread t owns tokens 4t..4t+3.
  const int t0 = tid << 2;
  const int m0 = tmask[t0], m1 = tmask[t0 + 1], m2 = tmask[t0 + 2], m3 = tmask[t0 + 3];
  const int cnt = m0 + m1 + m2 + m3;
  int incl = cnt;
  const int lane = tid & 63;
  #pragma unroll
  for (int o = 1; o < 64; o <<= 1) {
    const int v = __shfl_up(incl, o, 64);
    if (lane >= o) incl += v;
  }
  const int wv = tid >> 6;
  if (lane == 63) wbase[wv + 1] = incl;
  __syncthreads();
  if (tid == 0) {
    wbase[0] = 0;
    for (int i = 1; i <= 16; ++i) wbase[i] += wbase[i - 1];
  }
  __syncthreads();
  int pos = wbase[wv] + incl - cnt;
  const int K = wbase[16];
  int* sl = sel_list + b * NT;
  if (m0) sl[pos++] = t0;
  if (m1) sl[pos++] = t0 + 1;
  if (m2) sl[pos++] = t0 + 2;
  if (m3) sl[pos++] = t0 + 3;
  if (tid == 0) Karr[b] = K;
  for (int j = tid; j < NT; j += 1024)
    out_mask[b * NT + j] = (j < K) ? 1.0f : 0.0f;
}

// Pass 3: gather the K[b] selected rows (output rows beyond K already zeroed).
__global__ __launch_bounds__(256) void k_gather(
    const float4* __restrict__ x, const int* __restrict__ sel_list,
    const int* __restrict__ Karr, float4* __restrict__ outf)
{
  const int b = blockIdx.x;
  const int wv = threadIdx.x >> 6, lane = threadIdx.x & 63;
  const int K = Karr[b];
  for (int j = (blockIdx.y << 2) + wv; j < K; j += 64) {
    const int t = sel_list[b * NT + j];
    outf[((long long)(b * NT + j) << 6) + lane] = x[((long long)(b * NT + t) << 6) + lane];
  }
}

extern "C" void kernel_launch(void* const* d_in, const int* in_sizes, int n_in,
                              void* d_out, int out_size, void* d_ws, size_t ws_size,
                              hipStream_t stream)
{
  const float4* x = (const float4*)d_in[0];
  const float4* q = (const float4*)d_in[1];
  float* out = (float*)d_out;
  float* out_mask = out + (size_t)NB * NT * ND;

  // ws layout: [0, 2 MiB) f64 token scores | [2,3 MiB) int sel_list | [3 MiB) int K[NB]
  double* tok = (double*)d_ws;
  int* sel    = (int*)((char*)d_ws + (size_t)NB * NT * 8);
  int* Karr   = (int*)((char*)d_ws + (size_t)NB * NT * 12);

  k_score_zero<<<NB * NT / 4, 256, 0, stream>>>(x, q, tok, (float4*)d_out);
  k_tree<<<NB, 1024, 0, stream>>>(tok, sel, Karr, out_mask);
  k_gather<<<dim3(NB, 16), 256, 0, stream>>>(x, sel, Karr, (float4*)d_out);
}